// Round 1
// baseline (451.963 us; speedup 1.0000x reference)
//
#include <hip/hip_runtime.h>

// Problem: out[b,s,k] = sum_n x[b,s,n] * W[k,n] + bias[k]
// W[k,n] = (W_q[k,n] - zeros[k,n/64]) * scales[k,n/64] * scale2[k] * mask[k,n]
// M = B*S = 8192, N (reduction/in_features) = 4096, K (out_features) = 4096.

#define M_DIM 8192
#define N_DIM 4096
#define K_DIM 4096

typedef __bf16 bf16;
typedef __attribute__((ext_vector_type(8))) bf16 bf16x8;
typedef __attribute__((ext_vector_type(4))) float f32x4;

// ---------------------------------------------------------------- pre-pass 1
// x (f32) -> bf16, vectorized 8 elems/thread-iter.
__global__ __launch_bounds__(256) void cvt_x_kernel(const float* __restrict__ x,
                                                    bf16* __restrict__ xb) {
  const long total = (long)M_DIM * N_DIM / 8;  // 4,194,304
  const long stride = (long)gridDim.x * blockDim.x;
  for (long t = (long)blockIdx.x * blockDim.x + threadIdx.x; t < total; t += stride) {
    const long e = t * 8;
    const float4 v0 = *reinterpret_cast<const float4*>(x + e);
    const float4 v1 = *reinterpret_cast<const float4*>(x + e + 4);
    bf16x8 o;
    o[0] = (bf16)v0.x; o[1] = (bf16)v0.y; o[2] = (bf16)v0.z; o[3] = (bf16)v0.w;
    o[4] = (bf16)v1.x; o[5] = (bf16)v1.y; o[6] = (bf16)v1.z; o[7] = (bf16)v1.w;
    *reinterpret_cast<bf16x8*>(xb + e) = o;
  }
}

// ---------------------------------------------------------------- pre-pass 2
// Dequantize W -> bf16. One thread handles 8 consecutive n (same group of 64).
__global__ __launch_bounds__(256) void deq_w_kernel(const int* __restrict__ Wq,
                                                    const float* __restrict__ scales,
                                                    const float* __restrict__ zeros,
                                                    const int* __restrict__ mask,
                                                    const float* __restrict__ scale2,
                                                    bf16* __restrict__ wb) {
  const int total = K_DIM * (N_DIM / 8);  // 2,097,152
  const int stride = gridDim.x * blockDim.x;
  for (int t = blockIdx.x * blockDim.x + threadIdx.x; t < total; t += stride) {
    const int k = t >> 9;              // N_DIM/8 = 512 octets per row
    const int n0 = (t & 511) << 3;
    const int g = n0 >> 6;
    const float s = scales[(k << 6) + g] * scale2[k];
    const float z = zeros[(k << 6) + g];
    const long base = (long)k * N_DIM + n0;
    const int4 q0 = *reinterpret_cast<const int4*>(Wq + base);
    const int4 q1 = *reinterpret_cast<const int4*>(Wq + base + 4);
    const int4 m0 = *reinterpret_cast<const int4*>(mask + base);
    const int4 m1 = *reinterpret_cast<const int4*>(mask + base + 4);
    bf16x8 o;
    o[0] = (bf16)(((float)q0.x - z) * s * (float)m0.x);
    o[1] = (bf16)(((float)q0.y - z) * s * (float)m0.y);
    o[2] = (bf16)(((float)q0.z - z) * s * (float)m0.z);
    o[3] = (bf16)(((float)q0.w - z) * s * (float)m0.w);
    o[4] = (bf16)(((float)q1.x - z) * s * (float)m1.x);
    o[5] = (bf16)(((float)q1.y - z) * s * (float)m1.y);
    o[6] = (bf16)(((float)q1.z - z) * s * (float)m1.z);
    o[7] = (bf16)(((float)q1.w - z) * s * (float)m1.w);
    *reinterpret_cast<bf16x8*>(wb + base) = o;
  }
}

// ---------------------------------------------------------------- GEMM
// m97 structure: 128x128 tile, BK=32, 4 waves each owning a 64x64 quadrant,
// global_load_lds width=16 staging, single-buffered LDS, 16 MFMA / K-step / wave.
__device__ inline void gload_lds16(const bf16* g, bf16* l) {
  __builtin_amdgcn_global_load_lds(
      (const __attribute__((address_space(1))) void*)g,
      (__attribute__((address_space(3))) void*)l, 16, 0, 0);
}

__global__ __launch_bounds__(256) void gemm_kernel(const bf16* __restrict__ xb,
                                                   const bf16* __restrict__ wb,
                                                   const float* __restrict__ bias,
                                                   float* __restrict__ out) {
  __shared__ bf16 Alds[128 * 32];
  __shared__ bf16 Blds[128 * 32];

  const int tid = threadIdx.x;
  const int lane = tid & 63;
  const int wave = tid >> 6;
  const int wr = wave >> 1;   // wave row quadrant (0..1)
  const int wc = wave & 1;    // wave col quadrant (0..1)

  // XCD-aware bijective swizzle: nwg = 2048, divisible by 8.
  const int gid = blockIdx.x;
  const int swz = ((gid & 7) << 8) | (gid >> 3);
  const int bm = swz & 63;    // 64 M-tiles; consecutive swz share bk (B panel in L2)
  const int bk = swz >> 6;    // 32 K-tiles
  const long m0 = (long)bm * 128;
  const long k0 = (long)bk * 128;

  // Staging: per K-step the A tile is 128x32 bf16 = 8 KB (same for B).
  // Wave w, round r in {0,1}: LDS bytes [r*4096 + w*1024 + lane*16).
  // Matching global element: row = r*64 + w*16 + lane/4, col = (lane%4)*8.
  const int srow = wave * 16 + (lane >> 2);
  const int scol = (lane & 3) * 8;
  const bf16* gA = xb + (m0 + srow) * N_DIM + scol;
  const bf16* gB = wb + (k0 + srow) * N_DIM + scol;
  bf16* lA = Alds + wave * 512;  // bf16 elements; +lane*8 implicit in HW
  bf16* lB = Blds + wave * 512;

  f32x4 acc[4][4] = {};

  for (int n0 = 0; n0 < N_DIM; n0 += 32) {
    gload_lds16(gA + n0, lA);
    gload_lds16(gA + n0 + 64 * N_DIM, lA + 2048);
    gload_lds16(gB + n0, lB);
    gload_lds16(gB + n0 + 64 * N_DIM, lB + 2048);
    __syncthreads();  // compiler drains vmcnt(0) before s_barrier

    // Fragments: A lane l holds row (l&15), 8 contiguous k at (l>>4)*8.
    // (A/B k-maps are the same (lanegroup,slot)->k bijection, so any
    //  consistent contiguous load is correct.)
    const int kof = (lane >> 4) * 8;
    const int ar = wr * 64 + (lane & 15);
    const int br = wc * 64 + (lane & 15);
    bf16x8 af[4], bfr[4];
#pragma unroll
    for (int i = 0; i < 4; ++i)
      af[i] = *reinterpret_cast<const bf16x8*>(&Alds[(ar + i * 16) * 32 + kof]);
#pragma unroll
    for (int i = 0; i < 4; ++i)
      bfr[i] = *reinterpret_cast<const bf16x8*>(&Blds[(br + i * 16) * 32 + kof]);

#pragma unroll
    for (int mi = 0; mi < 4; ++mi)
#pragma unroll
      for (int ni = 0; ni < 4; ++ni)
        acc[mi][ni] = __builtin_amdgcn_mfma_f32_16x16x32_bf16(af[mi], bfr[ni],
                                                              acc[mi][ni], 0, 0, 0);
    __syncthreads();
  }

  // Epilogue: C/D layout col = lane&15, row = (lane>>4)*4 + r (verified m89/m91).
  const int ocol = (int)k0 + wc * 64 + (lane & 15);
  const int orow = (int)m0 + wr * 64 + (lane >> 4) * 4;
#pragma unroll
  for (int ni = 0; ni < 4; ++ni) {
    const float bv = bias[ocol + ni * 16];
#pragma unroll
    for (int mi = 0; mi < 4; ++mi) {
#pragma unroll
      for (int r = 0; r < 4; ++r) {
        out[(long)(orow + mi * 16 + r) * K_DIM + ocol + ni * 16] =
            acc[mi][ni][r] + bv;
      }
    }
  }
}

// ---------------------------------------------------------------- launch
extern "C" void kernel_launch(void* const* d_in, const int* in_sizes, int n_in,
                              void* d_out, int out_size, void* d_ws, size_t ws_size,
                              hipStream_t stream) {
  const float* x      = (const float*)d_in[0];
  const int*   Wq     = (const int*)d_in[1];
  const float* scales = (const float*)d_in[2];
  const float* zeros  = (const float*)d_in[3];
  const int*   mask   = (const int*)d_in[4];
  const float* scale2 = (const float*)d_in[5];
  const float* bias   = (const float*)d_in[6];
  float* out = (float*)d_out;

  // Workspace layout: x_bf16 (67,108,864 B) | W_bf16 (33,554,432 B)
  bf16* xb = (bf16*)d_ws;
  bf16* wb = (bf16*)((char*)d_ws + (size_t)M_DIM * N_DIM * 2);

  cvt_x_kernel<<<2048, 256, 0, stream>>>(x, xb);
  deq_w_kernel<<<2048, 256, 0, stream>>>(Wq, scales, zeros, mask, scale2, wb);

  // Grid: (M/128) * (K/128) = 64 * 32 = 2048 blocks.
  gemm_kernel<<<2048, 256, 0, stream>>>(xb, wb, bias, out);
}

// Round 2
// 321.347 us; speedup vs baseline: 1.4065x; 1.4065x over previous
//
#include <hip/hip_runtime.h>

// out[b,s,k] = sum_n x[b,s,n] * W[k,n] + bias[k]
// W[k,n] = (W_q[k,n] - zeros[k,n/64]) * scales[k,n/64] * scale2[k] * mask[k,n]
// M = B*S = 8192 (rows of x), N = 4096 (reduction), K = 4096 (out features).

#define M_DIM 8192
#define N_DIM 4096
#define K_DIM 4096
#define BK 32
#define NT (N_DIM / BK)  // 128 K-tiles

typedef __bf16 bf16;
typedef __attribute__((ext_vector_type(8))) bf16 bf16x8;
typedef __attribute__((ext_vector_type(4))) float f32x4;

// ---------------------------------------------------------------- pre-pass 1
__global__ __launch_bounds__(256) void cvt_x_kernel(const float* __restrict__ x,
                                                    bf16* __restrict__ xb) {
  const long total = (long)M_DIM * N_DIM / 8;
  const long stride = (long)gridDim.x * blockDim.x;
  for (long t = (long)blockIdx.x * blockDim.x + threadIdx.x; t < total; t += stride) {
    const long e = t * 8;
    const float4 v0 = *reinterpret_cast<const float4*>(x + e);
    const float4 v1 = *reinterpret_cast<const float4*>(x + e + 4);
    bf16x8 o;
    o[0] = (bf16)v0.x; o[1] = (bf16)v0.y; o[2] = (bf16)v0.z; o[3] = (bf16)v0.w;
    o[4] = (bf16)v1.x; o[5] = (bf16)v1.y; o[6] = (bf16)v1.z; o[7] = (bf16)v1.w;
    *reinterpret_cast<bf16x8*>(xb + e) = o;
  }
}

// ---------------------------------------------------------------- pre-pass 2
__global__ __launch_bounds__(256) void deq_w_kernel(const int* __restrict__ Wq,
                                                    const float* __restrict__ scales,
                                                    const float* __restrict__ zeros,
                                                    const int* __restrict__ mask,
                                                    const float* __restrict__ scale2,
                                                    bf16* __restrict__ wb) {
  const int total = K_DIM * (N_DIM / 8);
  const int stride = gridDim.x * blockDim.x;
  for (int t = blockIdx.x * blockDim.x + threadIdx.x; t < total; t += stride) {
    const int k = t >> 9;
    const int n0 = (t & 511) << 3;
    const int g = n0 >> 6;
    const float s = scales[(k << 6) + g] * scale2[k];
    const float z = zeros[(k << 6) + g];
    const long base = (long)k * N_DIM + n0;
    const int4 q0 = *reinterpret_cast<const int4*>(Wq + base);
    const int4 q1 = *reinterpret_cast<const int4*>(Wq + base + 4);
    const int4 m0 = *reinterpret_cast<const int4*>(mask + base);
    const int4 m1 = *reinterpret_cast<const int4*>(mask + base + 4);
    bf16x8 o;
    o[0] = (bf16)(((float)q0.x - z) * s * (float)m0.x);
    o[1] = (bf16)(((float)q0.y - z) * s * (float)m0.y);
    o[2] = (bf16)(((float)q0.z - z) * s * (float)m0.z);
    o[3] = (bf16)(((float)q0.w - z) * s * (float)m0.w);
    o[4] = (bf16)(((float)q1.x - z) * s * (float)m1.x);
    o[5] = (bf16)(((float)q1.y - z) * s * (float)m1.y);
    o[6] = (bf16)(((float)q1.z - z) * s * (float)m1.z);
    o[7] = (bf16)(((float)q1.w - z) * s * (float)m1.w);
    *reinterpret_cast<bf16x8*>(wb + base) = o;
  }
}

// ---------------------------------------------------------------- GEMM
// 256x256 tile, BK=32, 8 waves (2M x 4N), each wave owns 128x64 output.
// LDS: ring of 4 K-tile slots, each 32 KB (A 256x32 bf16 + B 256x32 bf16),
// total 128 KiB. Prefetch distance 3 tiles; counted vmcnt(8) — never drain
// in steady state (T4). One barrier per K-step.
//
// LDS layout (per A/B region, 16 KB): logical (row 0..255, slot 0..3 of 8
// bf16 each) stored at byte (row>>1)*128 + x*16 where
//   x = ((row&1)*4 + slot) ^ ((row>>1)&7)               (T2 swizzle)
// global_load_lds writes linearly, so the per-lane GLOBAL source address is
// pre-permuted by the same involution (rule 21: both-sides-or-neither).
__device__ inline void gload16(const bf16* g, bf16* l) {
  __builtin_amdgcn_global_load_lds(
      (const __attribute__((address_space(1))) void*)g,
      (__attribute__((address_space(3))) void*)l, 16, 0, 0);
}

__global__ __launch_bounds__(512, 2) void gemm_kernel(const bf16* __restrict__ xb,
                                                      const bf16* __restrict__ wb,
                                                      const float* __restrict__ bias,
                                                      float* __restrict__ out) {
  __shared__ bf16 lds[65536];  // 128 KiB: 4 slots x (8192 A + 8192 B) elements

  const int tid = threadIdx.x;
  const int lane = tid & 63;
  const int w = tid >> 6;
  const int wr = w >> 2;  // 0..1  (M half)
  const int wc = w & 3;   // 0..3  (N quarter)

  // T1: bijective XCD swizzle; nwg = 512, 512 % 8 == 0.
  const int gid = blockIdx.x;
  const int swz = ((gid & 7) << 6) | (gid >> 3);
  const int bm = swz & 31;  // 32 M-tiles; consecutive swz share bk (B panel in XCD L2)
  const int bk = swz >> 5;  // 16 K-tiles
  const long m0 = (long)bm * 256;
  const long k0 = (long)bk * 256;

  // Staging source decode: linear region byte p -> logical (row, slot).
  const bf16* srcA0; const bf16* srcA1; const bf16* srcB0; const bf16* srcB1;
  {
    const int p0 = w * 1024 + lane * 16;
    const int rp0 = p0 >> 7;
    const int v0 = ((p0 >> 4) & 7) ^ (rp0 & 7);
    const int row0 = rp0 * 2 + (v0 >> 2), col0 = (v0 & 3) * 8;
    const int p1 = 8192 + w * 1024 + lane * 16;
    const int rp1 = p1 >> 7;
    const int v1 = ((p1 >> 4) & 7) ^ (rp1 & 7);
    const int row1 = rp1 * 2 + (v1 >> 2), col1 = (v1 & 3) * 8;
    srcA0 = xb + (m0 + row0) * N_DIM + col0;
    srcA1 = xb + (m0 + row1) * N_DIM + col1;
    srcB0 = wb + (k0 + row0) * N_DIM + col0;
    srcB1 = wb + (k0 + row1) * N_DIM + col1;
  }

  // ds_read fragment offsets (elements). Lane reads row wr*128+(lane&15)+mi*16,
  // k-slot lane>>4. Swizzle x is mi-independent (mi*16 rows ≡ 0 mod 8 pairs).
  const int halfrow = (lane & 15) >> 1;
  const int xsw = (((lane & 1) << 2) | (lane >> 4)) ^ halfrow;
  const int frBase = halfrow * 64 + xsw * 8;
  const int aOff = wr * 4096 + frBase;         // within A region (+ mi*512)
  const int bOff = 8192 + wc * 2048 + frBase;  // within slot (+ ni*512)

  auto STAGE = [&](int t) {
    bf16* base = lds + (t & 3) * 16384;
    const int ko = t * BK;
    gload16(srcA0 + ko, base + w * 512);
    gload16(srcA1 + ko, base + 4096 + w * 512);
    gload16(srcB0 + ko, base + 8192 + w * 512);
    gload16(srcB1 + ko, base + 12288 + w * 512);
  };

  f32x4 acc[8][4] = {};

  // Prologue: 3 tiles in flight; vmcnt(8) => tile 0 landed (all threads).
  STAGE(0); STAGE(1); STAGE(2);
  asm volatile("s_waitcnt vmcnt(8)" ::: "memory");
  asm volatile("s_barrier" ::: "memory");

  for (int t = 0; t < NT; ++t) {
    const bf16* base = lds + (t & 3) * 16384;
    bf16x8 af[8], bfr[4];
#pragma unroll
    for (int mi = 0; mi < 8; ++mi)
      af[mi] = *reinterpret_cast<const bf16x8*>(base + aOff + mi * 512);
#pragma unroll
    for (int ni = 0; ni < 4; ++ni)
      bfr[ni] = *reinterpret_cast<const bf16x8*>(base + bOff + ni * 512);

    if (t + 3 < NT) STAGE(t + 3);  // targets slot (t-1)&3: reads done < barrier(t-1)

    // vmcnt: tile t+1 must be landed before any wave's reads at iter t+1.
    if (t < NT - 3)       asm volatile("s_waitcnt vmcnt(8)" ::: "memory");
    else if (t == NT - 3) asm volatile("s_waitcnt vmcnt(4)" ::: "memory");
    else                  asm volatile("s_waitcnt vmcnt(0)" ::: "memory");
    // lgkm drain pre-barrier: makes this iter's reads complete before the
    // barrier, so next iter's STAGE into this slot is WAR-safe w/ 1 barrier.
    asm volatile("s_waitcnt lgkmcnt(0)" ::: "memory");
    asm volatile("s_barrier" ::: "memory");
    __builtin_amdgcn_sched_barrier(0);

    __builtin_amdgcn_s_setprio(1);
#pragma unroll
    for (int mi = 0; mi < 8; ++mi)
#pragma unroll
      for (int ni = 0; ni < 4; ++ni)
        acc[mi][ni] = __builtin_amdgcn_mfma_f32_16x16x32_bf16(af[mi], bfr[ni],
                                                              acc[mi][ni], 0, 0, 0);
    __builtin_amdgcn_s_setprio(0);
  }

  // Epilogue. C/D: col = lane&15 (K-dim), row = (lane>>4)*4 + r (M-dim).
  const int ocol0 = (int)k0 + wc * 64 + (lane & 15);
  const int orow0 = (int)m0 + wr * 128 + (lane >> 4) * 4;
#pragma unroll
  for (int ni = 0; ni < 4; ++ni) {
    const float bv = bias[ocol0 + ni * 16];
#pragma unroll
    for (int mi = 0; mi < 8; ++mi)
#pragma unroll
      for (int r = 0; r < 4; ++r)
        out[(long)(orow0 + mi * 16 + r) * K_DIM + ocol0 + ni * 16] =
            acc[mi][ni][r] + bv;
  }
}

// ---------------------------------------------------------------- launch
extern "C" void kernel_launch(void* const* d_in, const int* in_sizes, int n_in,
                              void* d_out, int out_size, void* d_ws, size_t ws_size,
                              hipStream_t stream) {
  const float* x      = (const float*)d_in[0];
  const int*   Wq     = (const int*)d_in[1];
  const float* scales = (const float*)d_in[2];
  const float* zeros  = (const float*)d_in[3];
  const int*   mask   = (const int*)d_in[4];
  const float* scale2 = (const float*)d_in[5];
  const float* bias   = (const float*)d_in[6];
  float* out = (float*)d_out;

  bf16* xb = (bf16*)d_ws;
  bf16* wb = (bf16*)((char*)d_ws + (size_t)M_DIM * N_DIM * 2);

  cvt_x_kernel<<<2048, 256, 0, stream>>>(x, xb);
  deq_w_kernel<<<2048, 256, 0, stream>>>(Wq, scales, zeros, mask, scale2, wb);

  // Grid: (M/256) * (K/256) = 32 * 16 = 512 blocks, 512 threads.
  gemm_kernel<<<512, 512, 0, stream>>>(xb, wb, bias, out);
}